// Round 7
// baseline (254.671 us; speedup 1.0000x reference)
//
#include <hip/hip_runtime.h>
#include <hip/hip_bf16.h>

// Problem constants (B,DIM,H,W)=(4,256,64,64), DSTATE=64, EXPAND=2, DCONV=4
// DINNER=512, HEADDIM=64, NHEADS=8, DINPROJ=1160, CONVDIM=640, EPS=1e-5
#define EPSF 1e-5f

typedef unsigned short u16;
typedef __attribute__((ext_vector_type(8))) short short8;   // 8 x bf16 MFMA operand
typedef __attribute__((ext_vector_type(4))) float f32x4;    // MFMA accumulator

__device__ __forceinline__ float sigf(float x){ return 1.f/(1.f+__expf(-x)); }
__device__ __forceinline__ float siluf(float x){ return x/(1.f+__expf(-x)); }
__device__ __forceinline__ u16 f2bf(float x){ __hip_bfloat16 h = __float2bfloat16(x); return *reinterpret_cast<u16*>(&h); }
__device__ __forceinline__ float bf2f(u16 u){ __hip_bfloat16 h; *reinterpret_cast<u16*>(&h) = u; return __bfloat162float(h); }

union BF8 { short8 v; u16 h[8]; uint4 q; };

__device__ __forceinline__ short8 ldg_frag(const u16* p){
  BF8 u; u.q = *(const uint4*)p; return u.v;
}
#define MFMA16(a,b,c) __builtin_amdgcn_mfma_f32_16x16x32_bf16((a),(b),(c),0,0,0)

// ---------------- K0: channel LayerNorm, x (B,C,H,W) -> xn bf16 (B,H,W,C) ----------------
__global__ __launch_bounds__(256) void k_ln(const float* __restrict__ x,
                                            const float* __restrict__ g,
                                            const float* __restrict__ b,
                                            u16* __restrict__ xn){
  __shared__ float XL[256][65];
  __shared__ float red[2][4][64];
  __shared__ float muL[64], rsL[64];
  int blk = blockIdx.x; int bb = blk>>6, h = blk&63;
  int t = threadIdx.x;
  const float* xb = x + ((size_t)bb*256*4096) + h*64;
  for(int i=0;i<64;i++){ int idx = t + 256*i; int c = idx>>6, w = idx&63;
    XL[c][w] = xb[(size_t)c*4096 + w]; }
  __syncthreads();
  { int w = t & 63, q = t >> 6;
    float s1=0, s2=0;
    for(int c=q*64;c<q*64+64;c++){ float v = XL[c][w]; s1+=v; s2+=v*v; }
    red[0][q][w]=s1; red[1][q][w]=s2; }
  __syncthreads();
  if(t<64){ float a=0,c2=0;
    for(int q=0;q<4;q++){a+=red[0][q][t]; c2+=red[1][q][t];}
    float mu=a*(1.f/256.f); float var=c2*(1.f/256.f)-mu*mu;
    muL[t]=mu; rsL[t]=rsqrtf(var+EPSF); }
  __syncthreads();
  u16* xnb = xn + (size_t)(bb*64+h)*64*256;
  for(int i=0;i<64;i++){ int idx = t + 256*i; int w = idx>>8, c = idx&255;
    float v = (XL[c][w]-muL[w])*rsL[w]*g[c]+b[c];
    xnb[w*256 + c] = f2bf(v); }
}

// ---------------- K1a: pack Wi (256x1160 f32) into MFMA B-fragments, bf16 ----------------
__global__ __launch_bounds__(256) void k_packWi(const float* __restrict__ Wi,
                                                u16* __restrict__ WiF){
  int f = blockIdx.x*256 + threadIdx.x;   // 37376 threads exactly
  int lane = f & 63, kk = (f>>6)&7, ji = f>>9;
  int g = lane>>4, c16 = lane&15;
  int j = ji*16 + c16;
  BF8 o;
  #pragma unroll
  for(int i=0;i<8;i++){
    int k = kk*32 + g*8 + i;
    o.h[i] = (j < 1160) ? f2bf(Wi[(size_t)k*1160 + j]) : (u16)0;
  }
  *(uint4*)(WiF + (size_t)f*8) = o.q;
}

// ---------------- K1b: pack Wo (512x256 f32) into MFMA B-fragment order, bf16 ----------------
__global__ __launch_bounds__(256) void k_pack(const float* __restrict__ Wo,
                                              u16* __restrict__ WF){
  int f = blockIdx.x*256 + threadIdx.x;   // 16384 threads
  int c16 = f&15, g=(f>>4)&3, kk=(f>>6)&15, ci=f>>10;
  int c = ci*16 + c16;
  #pragma unroll
  for(int i=0;i<8;i++){
    int k = kk*32 + g*8 + i;
    WF[(size_t)f*8 + i] = f2bf(Wo[(size_t)k*256 + c]);
  }
}

// ---------------- K1c: W1 (256x256 f32, row-major [o][c]) -> bf16 copy ----------------
__global__ __launch_bounds__(256) void k_packW1(const float* __restrict__ W1,
                                                u16* __restrict__ W1b){
  int i = (blockIdx.x*256 + threadIdx.x)*4;
  float4 v = *(const float4*)(W1 + i);
  W1b[i+0]=f2bf(v.x); W1b[i+1]=f2bf(v.y); W1b[i+2]=f2bf(v.z); W1b[i+3]=f2bf(v.w);
}

// ---------------- K1: MFMA in-projection + conv(fwd & bwd) + silu + softplus ----------------
// grid (2, 256): blockIdx.y = seq, blockIdx.x = y-split.
// y takes z-tiles [16y,16y+16), xBC half hh=y (tiles 32+20y .. +19, 320 channels + conv);
// y==1 wave 7 also does the dt tile (ji=72).
__global__ __launch_bounds__(512, 2) void k_proj2(const u16* __restrict__ xn,
    const u16* __restrict__ WiF, const float* __restrict__ convw,
    const float* __restrict__ convb, const float* __restrict__ dtb,
    const float* __restrict__ alog,
    u16* __restrict__ zg, u16* __restrict__ xf, u16* __restrict__ xbw,
    float* __restrict__ dtp, float* __restrict__ dtA, int dirV){
  __shared__ u16 XL[64][264];      // A-tile, bf16 (pad 264)          33.8 KB
  __shared__ u16 RAW[64][328];     // xBC half, bf16 (pad 328)        42.0 KB
  int y = blockIdx.x; int s = blockIdx.y;
  int bb = s>>6, r = s&63;
  int t = threadIdx.x; int w = t>>6, lane = t&63, g = lane>>4, c16 = lane&15;

  // stage xn rows -> XL (each thread 64B)
  { int l = t>>3, cb = (t&7)*32;
    int row = dirV ? ((bb*64+l)*64 + r) : ((bb*64+r)*64 + l);
    const uint4* src = (const uint4*)(xn + (size_t)row*256 + cb);
    uint4 v0=src[0], v1=src[1], v2=src[2], v3=src[3];
    uint4* dst = (uint4*)&XL[l][cb];
    dst[0]=v0; dst[1]=v1; dst[2]=v2; dst[3]=v3;
  }
  __syncthreads();

  #define AFRAG(li,kk) (*(const short8*)&XL[(li)*16 + c16][(kk)*32 + g*8])

  // ---- Z part: tiles [16y,16y+16), wave w -> 2 tiles; silu -> zg ----
  #pragma unroll 1
  for(int j2=0;j2<2;++j2){
    int ji = y*16 + w*2 + j2;
    f32x4 acc0={0.f,0.f,0.f,0.f}, acc1=acc0, acc2=acc0, acc3=acc0;
    #pragma unroll
    for(int kk=0;kk<8;++kk){
      short8 bf = ldg_frag(WiF + ((size_t)(ji*8+kk)*64 + lane)*8);
      acc0 = MFMA16(AFRAG(0,kk), bf, acc0);
      acc1 = MFMA16(AFRAG(1,kk), bf, acc1);
      acc2 = MFMA16(AFRAG(2,kk), bf, acc2);
      acc3 = MFMA16(AFRAG(3,kk), bf, acc3);
    }
    int col = ji*16 + c16;
    #pragma unroll
    for(int r2=0;r2<4;r2++){
      zg[(size_t)(s*64 +  0 + g*4 + r2)*512 + col] = f2bf(siluf(acc0[r2]));
      zg[(size_t)(s*64 + 16 + g*4 + r2)*512 + col] = f2bf(siluf(acc1[r2]));
      zg[(size_t)(s*64 + 32 + g*4 + r2)*512 + col] = f2bf(siluf(acc2[r2]));
      zg[(size_t)(s*64 + 48 + g*4 + r2)*512 + col] = f2bf(siluf(acc3[r2]));
    }
  }

  // ---- xBC half hh=y: GEMM -> RAW bf16 -> conv(fwd+bwd) -> xf/xbw ----
  {
    int tb  = (w<4) ? 3*w : 12 + 2*(w-4);
    int cnt = (w<4) ? 3 : 2;
    #pragma unroll 1
    for(int u=0; u<cnt; ++u){
      int j4 = tb + u;                 // 0..19 within half
      int ji = 32 + y*20 + j4;         // global tile
      f32x4 acc0={0.f,0.f,0.f,0.f}, acc1=acc0, acc2=acc0, acc3=acc0;
      #pragma unroll
      for(int kk=0;kk<8;++kk){
        short8 bf = ldg_frag(WiF + ((size_t)(ji*8+kk)*64 + lane)*8);
        acc0 = MFMA16(AFRAG(0,kk), bf, acc0);
        acc1 = MFMA16(AFRAG(1,kk), bf, acc1);
        acc2 = MFMA16(AFRAG(2,kk), bf, acc2);
        acc3 = MFMA16(AFRAG(3,kk), bf, acc3);
      }
      int cl = j4*16 + c16;
      #pragma unroll
      for(int r2=0;r2<4;r2++){
        RAW[ 0 + g*4 + r2][cl] = f2bf(acc0[r2]);
        RAW[16 + g*4 + r2][cl] = f2bf(acc1[r2]);
        RAW[32 + g*4 + r2][cl] = f2bf(acc2[r2]);
        RAW[48 + g*4 + r2][cl] = f2bf(acc3[r2]);
      }
    }
  }

  // ---- dt tile (ji=72, cols 1152..1159): y==1, wave 7 ----
  if(y==1 && w==7){
    f32x4 acc0={0.f,0.f,0.f,0.f}, acc1=acc0, acc2=acc0, acc3=acc0;
    #pragma unroll
    for(int kk=0;kk<8;++kk){
      short8 bf = ldg_frag(WiF + ((size_t)(72*8+kk)*64 + lane)*8);
      acc0 = MFMA16(AFRAG(0,kk), bf, acc0);
      acc1 = MFMA16(AFRAG(1,kk), bf, acc1);
      acc2 = MFMA16(AFRAG(2,kk), bf, acc2);
      acc3 = MFMA16(AFRAG(3,kk), bf, acc3);
    }
    if(c16 < 8){
      int hd = c16;
      float A = -expf(alog[hd]);
      float bias = dtb[hd];
      #pragma unroll
      for(int li=0;li<4;li++){
        f32x4 a = (li==0)?acc0 : (li==1)?acc1 : (li==2)?acc2 : acc3;
        #pragma unroll
        for(int r2=0;r2<4;r2++){
          int l = li*16 + g*4 + r2;
          float v = a[r2] + bias;
          float sp = (v>20.f)? v : log1pf(expf(v));
          dtp[(size_t)(s*8+hd)*64 + l] = sp;
          dtA[(size_t)(s*8+hd)*64 + l] = sp*A;
        }
      }
    }
  }
  __syncthreads();

  // ---- conv: threads 0..319, one channel each; sliding windows ----
  if(t < 320){
    int C = y*320 + t;
    float4 cw4 = *(const float4*)(convw + C*4);
    float cb_ = convb[C];
    float fx1=0.f,fx2=0.f,fx3=0.f, by1=0.f,by2=0.f,by3=0.f;
    #pragma unroll 1
    for(int l=0;l<64;++l){
      float fx0 = bf2f(RAW[l][t]);
      float by0 = bf2f(RAW[63-l][t]);
      // fwd: w0*x[l-3]+w1*x[l-2]+w2*x[l-1]+w3*x[l]
      float of = cb_ + cw4.w*fx0 + cw4.z*fx1 + cw4.y*fx2 + cw4.x*fx3;
      // bwd: reversed taps on reversed sequence (zero-init windows = clipping)
      float ob = cb_ + cw4.w*by0 + cw4.z*by1 + cw4.y*by2 + cw4.x*by3;
      size_t gi = (size_t)(s*64+l)*640 + C;
      xf [gi] = f2bf(siluf(of));
      xbw[gi] = f2bf(siluf(ob));
      fx3=fx2; fx2=fx1; fx1=fx0;
      by3=by2; by2=by1; by1=by0;
    }
  }
  #undef AFRAG
}

// ---------------- K2: SSD-form scan (MFMA) + gate + RMSNorm + out-proj (MFMA) ----------------
__global__ __launch_bounds__(512, 2) void k_scan(
    const u16* __restrict__ xf, const u16* __restrict__ xbw,
    const float* __restrict__ dtp_g, const float* __restrict__ dtA_g,
    const u16* __restrict__ zg, const float* __restrict__ dskip,
    const float* __restrict__ normw, const u16* __restrict__ WF,
    u16* __restrict__ fout){
  // LDS: U [64][520] bf16 | XV [64][520] bf16 (X stage, then gated-V) | G [64][68] f32
  //      sL [8][64] f32 | dtL [8][64] f32 | nwL [512] f32   = 156672 B
  __shared__ __align__(16) char smem[156672];
  u16 (*U)[520]   = (u16(*)[520])smem;
  u16 (*XV)[520]  = (u16(*)[520])(smem + 66560);
  float (*Gl)[68] = (float(*)[68])(smem + 133120);
  float* sL  = (float*)(smem + 150528);
  float* dtL = (float*)(smem + 152576);
  float* nwL = (float*)(smem + 154624);

  int s = blockIdx.x, t = threadIdx.x;
  int w = t>>6, lane = t&63, g = lane>>4, c16 = lane&15;
  nwL[t] = normw[t];
  float dsk = dskip[w];

  #pragma unroll 1
  for(int dirb=0; dirb<2; ++dirb){
    __syncthreads();   // dir1: prior V reads / U writes done before restage
    const u16* xb = (dirb? xbw : xf) + (size_t)s*64*640;
    // ---- per-head prefix sum of dt*A in scan coords (wave-local) ----
    {
      int tt = dirb ? 63-lane : lane;
      float a = dtA_g[(s*8+w)*64 + tt];
      float d = dtp_g[(s*8+w)*64 + tt];
      #pragma unroll
      for(int off=1; off<64; off<<=1){
        float nb = __shfl_up(a, off, 64);
        if(lane >= off) a += nb;
      }
      sL[w*64+lane] = a;
      dtL[w*64+lane] = d;
    }
    // ---- G = C @ B^T : wave w computes 16x16 tiles 2w, 2w+1 (frags direct from global) ----
    #pragma unroll
    for(int tt2=0; tt2<2; ++tt2){
      int tile = 2*w + tt2, li = tile>>2, ji = tile&3;
      f32x4 acc = {0.f,0.f,0.f,0.f};
      #pragma unroll
      for(int kk=0; kk<2; ++kk){
        short8 af = ldg_frag(xb + (size_t)(li*16 + c16)*640 + 576 + kk*32 + g*8); // C rows
        short8 bf = ldg_frag(xb + (size_t)(ji*16 + c16)*640 + 512 + kk*32 + g*8); // B rows
        acc = MFMA16(af, bf, acc);
      }
      #pragma unroll
      for(int r=0;r<4;r++) Gl[li*16 + g*4 + r][ji*16 + c16] = acc[r];
    }
    // ---- stage X (cols 0..511) into XV ----
    #pragma unroll
    for(int it=0; it<8; ++it){
      int tr = (t>>6) + 8*it;
      int c0 = (t&63)*8;
      uint4 v = *(const uint4*)(xb + (size_t)tr*640 + c0);
      *(uint4*)&XV[tr][c0] = v;
    }
    __syncthreads();
    // ---- X-frags preload (own head's 64 cols; frees XV rows for V writes) ----
    short8 xfr[4][2];
    #pragma unroll
    for(int pi=0; pi<4; ++pi){
      #pragma unroll
      for(int kk=0; kk<2; ++kk){
        BF8 u;
        #pragma unroll
        for(int i=0;i<8;i++){
          int uu = kk*32 + g*8 + i;
          u.h[i] = XV[uu][w*64 + pi*16 + c16];
        }
        xfr[pi][kk] = u.v;
      }
    }
    // ---- per l-tile: build M fragments, Y = M@X, gate, write V ----
    #pragma unroll 1
    for(int li=0; li<4; ++li){
      int tr = li*16 + c16;            // A-frag row (scan coord)
      float sl = sL[w*64 + tr];
      short8 mfr[2];
      #pragma unroll
      for(int kk=0; kk<2; ++kk){
        BF8 u;
        #pragma unroll
        for(int i=0;i<8;i++){
          int uu = kk*32 + g*8 + i;
          float m = 0.f;
          if(uu <= tr){
            m = __expf(sl - sL[w*64+uu]) * dtL[w*64+uu] * Gl[tr][uu];
            if(uu == tr) m += dsk;     // Dskip folded into diagonal (exact)
          }
          u.h[i] = f2bf(m);
        }
        mfr[kk] = u.v;
      }
      #pragma unroll
      for(int pi=0; pi<4; ++pi){
        f32x4 acc = {0.f,0.f,0.f,0.f};
        acc = MFMA16(mfr[0], xfr[pi][0], acc);
        acc = MFMA16(mfr[1], xfr[pi][1], acc);
        #pragma unroll
        for(int r=0;r<4;r++){
          int trow = li*16 + g*4 + r;
          int lorig = dirb ? 63-trow : trow;
          int c = w*64 + pi*16 + c16;
          float zv = bf2f(zg[((size_t)(s*64 + lorig))*512 + c]);  // silu(z) pre-applied
          XV[lorig][c] = f2bf(acc[r] * zv);
        }
      }
    }
    __syncthreads();
    // ---- RMSNorm per row (over 512), accumulate 0.5*v*rs*normw into U ----
    #pragma unroll 1
    for(int rr=0; rr<8; ++rr){
      int l = w*8 + rr;
      BF8 u; u.q = *(const uint4*)&XV[l][lane*8];
      float vv[8]; float ss = 0.f;
      #pragma unroll
      for(int i=0;i<8;i++){ vv[i] = bf2f(u.h[i]); ss += vv[i]*vv[i]; }
      #pragma unroll
      for(int off=32; off>=1; off>>=1) ss += __shfl_xor(ss, off, 64);
      float rs = rsqrtf(ss*(1.f/512.f) + EPSF);
      BF8 o;
      if(dirb==0){
        #pragma unroll
        for(int i=0;i<8;i++) o.h[i] = f2bf(0.5f*vv[i]*rs*nwL[lane*8+i]);
      } else {
        BF8 p; p.q = *(const uint4*)&U[l][lane*8];
        #pragma unroll
        for(int i=0;i<8;i++) o.h[i] = f2bf(bf2f(p.h[i]) + 0.5f*vv[i]*rs*nwL[lane*8+i]);
      }
      *(uint4*)&U[l][lane*8] = o.q;
    }
  }
  __syncthreads();
  // ---- out-proj: fout[64][256] = U[64][512] @ Wo ; wave w owns c-tiles 2w,2w+1 ----
  #pragma unroll 1
  for(int ci0=0; ci0<2; ++ci0){
    int ci = w*2 + ci0;
    f32x4 acc0={0.f,0.f,0.f,0.f}, acc1=acc0, acc2=acc0, acc3=acc0;
    #pragma unroll 2
    for(int kk=0; kk<16; ++kk){
      short8 bfr = ldg_frag(WF + (size_t)((((ci*16+kk)*4+g)*16+c16)*8));
      short8 a0 = *(const short8*)&U[ 0+c16][kk*32+g*8];
      short8 a1 = *(const short8*)&U[16+c16][kk*32+g*8];
      short8 a2 = *(const short8*)&U[32+c16][kk*32+g*8];
      short8 a3 = *(const short8*)&U[48+c16][kk*32+g*8];
      acc0 = MFMA16(a0,bfr,acc0); acc1 = MFMA16(a1,bfr,acc1);
      acc2 = MFMA16(a2,bfr,acc2); acc3 = MFMA16(a3,bfr,acc3);
    }
    #define WR_TILE(LI, ACC) { \
      _Pragma("unroll") \
      for(int r=0;r<4;r++) \
        fout[((size_t)(s*64 + LI*16 + g*4 + r))*256 + ci*16 + c16] = f2bf(ACC[r]); }
    WR_TILE(0, acc0) WR_TILE(1, acc1) WR_TILE(2, acc2) WR_TILE(3, acc3)
    #undef WR_TILE
  }
}

// ---------------- K3: blend f_H/f_V (bf16) + 1x1 conv on MFMA + partial stats ----------------
__global__ __launch_bounds__(512) void k_blendgemm(const u16* __restrict__ fH,
    const u16* __restrict__ fV, const float* __restrict__ Q1,
    const float* __restrict__ Sx, const u16* __restrict__ W1b,
    float* __restrict__ out, float* __restrict__ stats){
  __shared__ u16 fg[64][264];              // blended tile, bf16
  __shared__ float asL[64], bsL[64];
  __shared__ float red[16];
  int blk = blockIdx.x; int bb = blk>>6, h = blk&63;
  int t = threadIdx.x;
  if(t<64){
    float qv = Q1[bb*4096 + h*64 + t];
    float sv = Sx[bb*4096 + h*64 + t];
    float al = sigf(qv);
    float sc = 0.5f + 0.5f*sv;
    asL[t] = al*sc; bsL[t] = (1.f-al)*sc;
  }
  __syncthreads();
  {
    int w = t>>3, cb = (t&7)*8;
    float aw = asL[w], bw = bsL[w];
    const u16* ph = fH + ((size_t)((bb*64+h)*64 + w))*256;
    const u16* pv = fV + ((size_t)((bb*64+w)*64 + h))*256;
    #pragma unroll
    for(int j=0;j<4;j++){
      int c0 = cb + j*64;
      BF8 a, b, o;
      a.q = *(const uint4*)(ph + c0);
      b.q = *(const uint4*)(pv + c0);
      #pragma unroll
      for(int i=0;i<8;i++) o.h[i] = f2bf(aw*bf2f(a.h[i]) + bw*bf2f(b.h[i]));
      *(uint4*)&fg[w][c0] = o.q;
    }
  }
  __syncthreads();
  int wv = t>>6, lane = t&63, g = lane>>4, c16 = lane&15;
  f32x4 acc[4][2];
  #pragma unroll
  for(int pi=0;pi<4;pi++){ acc[pi][0]=(f32x4){0.f,0.f,0.f,0.f}; acc[pi][1]=acc[pi][0]; }
  #pragma unroll 2
  for(int kk=0; kk<8; ++kk){
    short8 b0 = ldg_frag(W1b + (size_t)((wv*2+0)*16 + c16)*256 + kk*32 + g*8);
    short8 b1 = ldg_frag(W1b + (size_t)((wv*2+1)*16 + c16)*256 + kk*32 + g*8);
    #pragma unroll
    for(int pi=0; pi<4; ++pi){
      short8 a = *(const short8*)&fg[pi*16 + c16][kk*32 + g*8];
      acc[pi][0] = MFMA16(a, b0, acc[pi][0]);
      acc[pi][1] = MFMA16(a, b1, acc[pi][1]);
    }
  }
  float s1=0.f, s2=0.f;
  #pragma unroll
  for(int pi=0;pi<4;pi++){
    #pragma unroll
    for(int j=0;j<2;j++){
      int o = (wv*2+j)*16 + c16;
      int w0 = pi*16 + g*4;
      float4 vv = {acc[pi][j][0], acc[pi][j][1], acc[pi][j][2], acc[pi][j][3]};
      s1 += (vv.x+vv.y)+(vv.z+vv.w);
      s2 += (vv.x*vv.x+vv.y*vv.y)+(vv.z*vv.z+vv.w*vv.w);
      *(float4*)(out + (((size_t)(bb*256+o)*64 + h)*64 + w0)) = vv;
    }
  }
  #pragma unroll
  for(int off=32;off>=1;off>>=1){ s1+=__shfl_xor(s1,off,64); s2+=__shfl_xor(s2,off,64); }
  if(lane==0){ red[wv]=s1; red[8+wv]=s2; }
  __syncthreads();
  if(t==0){
    float a=0.f,b=0.f;
    #pragma unroll
    for(int i=0;i<8;i++){ a+=red[i]; b+=red[8+i]; }
    stats[blk*2+0]=a; stats[blk*2+1]=b;
  }
}

// ---------------- K4: per-batch global norm + exact GELU, in place on d_out ----------------
__global__ __launch_bounds__(256) void k_final(float* __restrict__ out,
    const float* __restrict__ stats, const float* __restrict__ gg,
    const float* __restrict__ gb){
  __shared__ float red[64][2];
  __shared__ float mv[2];
  int blk = blockIdx.x; int bb = blk>>6, h = blk&63;
  int t = threadIdx.x;
  if(t<64){ red[t][0] = stats[(bb*64+t)*2+0]; red[t][1] = stats[(bb*64+t)*2+1]; }
  __syncthreads();
  if(t==0){
    float s1=0.f,s2=0.f;
    for(int i=0;i<64;i++){ s1+=red[i][0]; s2+=red[i][1]; }
    float mu = s1*(1.f/1048576.f);
    float var = s2*(1.f/1048576.f) - mu*mu;
    mv[0]=mu; mv[1]=rsqrtf(var+EPSF);
  }
  __syncthreads();
  float mu = mv[0], rs = mv[1];
  for(int i=0;i<64;i++){ int idx=t+256*i; int o=idx>>6, w=idx&63;
    size_t gidx = (size_t)((bb*256+o)*64+h)*64+w;
    float v = out[gidx];
    float yn = (v-mu)*rs*gg[o] + gb[o];
    out[gidx] = 0.5f*yn*(1.f+erff(yn*0.70710678118654752f));
  }
}

extern "C" void kernel_launch(void* const* d_in, const int* in_sizes, int n_in,
                              void* d_out, int out_size, void* d_ws, size_t ws_size,
                              hipStream_t stream) {
  const float* x     = (const float*)d_in[0];
  const float* Q1    = (const float*)d_in[1];
  // d_in[2] = Q2 : unused by the reference
  const float* Sx    = (const float*)d_in[3];
  const float* lng   = (const float*)d_in[4];
  const float* lnb   = (const float*)d_in[5];
  const float* Wi    = (const float*)d_in[6];
  const float* convw = (const float*)d_in[7];
  const float* convb = (const float*)d_in[8];
  const float* dtb   = (const float*)d_in[9];
  const float* alog  = (const float*)d_in[10];
  const float* dskip = (const float*)d_in[11];
  const float* normw = (const float*)d_in[12];
  const float* Wo    = (const float*)d_in[13];
  const float* gg    = (const float*)d_in[14];
  const float* gb    = (const float*)d_in[15];
  const float* W1    = (const float*)d_in[16];
  float* out = (float*)d_out;
  char* ws = (char*)d_ws;

  // ws layout (~86 MiB):
  size_t o = 0;
  u16*   xnb  = (u16*)(ws + o);  o += (size_t)16384*256*2;        // 8 MB  xn bf16
  u16*   fHb  = (u16*)(ws + o);  o += (size_t)16384*256*2;        // 8 MB
  u16*   fVb  = (u16*)(ws + o);  o += (size_t)16384*256*2;        // 8 MB
  u16*   zgb  = (u16*)(ws + o);  o += (size_t)16384*512*2;        // 16 MB
  u16*   xfb  = (u16*)(ws + o);  o += (size_t)16384*640*2;        // 20 MB
  u16*   xbb  = (u16*)(ws + o);  o += (size_t)16384*640*2;        // 20 MB
  float* dtp  = (float*)(ws + o); o += (size_t)131072*4;          // 0.5 MB
  float* dtA  = (float*)(ws + o); o += (size_t)131072*4;          // 0.5 MB
  float* stats= (float*)(ws + o); o += 4096;
  u16*   WF   = (u16*)(ws + o);  o += (size_t)16384*8*2;          // 256 KB
  u16*   W1b  = (u16*)(ws + o);  o += (size_t)65536*2;            // 128 KB
  u16*   WiF  = (u16*)(ws + o);  o += (size_t)73*8*64*8*2;        // 584 KB

  k_ln<<<256, 256, 0, stream>>>(x, lng, lnb, xnb);
  k_packWi<<<146, 256, 0, stream>>>(Wi, WiF);
  k_pack<<<64, 256, 0, stream>>>(Wo, WF);
  k_packW1<<<64, 256, 0, stream>>>(W1, W1b);
  for(int dir=0; dir<2; dir++){
    k_proj2<<<dim3(2,256), 512, 0, stream>>>(xnb, WiF, convw, convb, dtb, alog,
                                             zgb, xfb, xbb, dtp, dtA, dir);
    k_scan<<<256, 512, 0, stream>>>(xfb, xbb, dtp, dtA, zgb, dskip, normw, WF,
                                    dir ? fVb : fHb);
  }
  k_blendgemm<<<256, 512, 0, stream>>>(fHb, fVb, Q1, Sx, W1b, out, stats);
  k_final<<<256, 256, 0, stream>>>(out, stats, gg, gb);
}

// Round 8
// 213.026 us; speedup vs baseline: 1.1955x; 1.1955x over previous
//
#include <hip/hip_runtime.h>
#include <hip/hip_bf16.h>

// Problem constants (B,DIM,H,W)=(4,256,64,64), DSTATE=64, EXPAND=2, DCONV=4
// DINNER=512, HEADDIM=64, NHEADS=8, DINPROJ=1160, CONVDIM=640, EPS=1e-5
#define EPSF 1e-5f

typedef unsigned short u16;
typedef __attribute__((ext_vector_type(8))) short short8;   // 8 x bf16 MFMA operand
typedef __attribute__((ext_vector_type(4))) float f32x4;    // MFMA accumulator

__device__ __forceinline__ float sigf(float x){ return 1.f/(1.f+__expf(-x)); }
__device__ __forceinline__ float siluf(float x){ return x/(1.f+__expf(-x)); }
__device__ __forceinline__ u16 f2bf(float x){ __hip_bfloat16 h = __float2bfloat16(x); return *reinterpret_cast<u16*>(&h); }
__device__ __forceinline__ float bf2f(u16 u){ __hip_bfloat16 h; *reinterpret_cast<u16*>(&h) = u; return __bfloat162float(h); }

union BF8 { short8 v; u16 h[8]; uint4 q; };

__device__ __forceinline__ short8 ldg_frag(const u16* p){
  BF8 u; u.q = *(const uint4*)p; return u.v;
}
#define MFMA16(a,b,c) __builtin_amdgcn_mfma_f32_16x16x32_bf16((a),(b),(c),0,0,0)

// ---------------- K0: channel LayerNorm, x (B,C,H,W) -> xn bf16 (B,H,W,C) ----------------
__global__ __launch_bounds__(256) void k_ln(const float* __restrict__ x,
                                            const float* __restrict__ g,
                                            const float* __restrict__ b,
                                            u16* __restrict__ xn){
  __shared__ float XL[256][65];
  __shared__ float red[2][4][64];
  __shared__ float muL[64], rsL[64];
  int blk = blockIdx.x; int bb = blk>>6, h = blk&63;
  int t = threadIdx.x;
  const float* xb = x + ((size_t)bb*256*4096) + h*64;
  for(int i=0;i<64;i++){ int idx = t + 256*i; int c = idx>>6, w = idx&63;
    XL[c][w] = xb[(size_t)c*4096 + w]; }
  __syncthreads();
  { int w = t & 63, q = t >> 6;
    float s1=0, s2=0;
    for(int c=q*64;c<q*64+64;c++){ float v = XL[c][w]; s1+=v; s2+=v*v; }
    red[0][q][w]=s1; red[1][q][w]=s2; }
  __syncthreads();
  if(t<64){ float a=0,c2=0;
    for(int q=0;q<4;q++){a+=red[0][q][t]; c2+=red[1][q][t];}
    float mu=a*(1.f/256.f); float var=c2*(1.f/256.f)-mu*mu;
    muL[t]=mu; rsL[t]=rsqrtf(var+EPSF); }
  __syncthreads();
  u16* xnb = xn + (size_t)(bb*64+h)*64*256;
  for(int i=0;i<64;i++){ int idx = t + 256*i; int w = idx>>8, c = idx&255;
    float v = (XL[c][w]-muL[w])*rsL[w]*g[c]+b[c];
    xnb[w*256 + c] = f2bf(v); }
}

// ---------------- K1a: pack Wi (256x1160 f32) into MFMA B-fragments, bf16 ----------------
// 73 col-tiles of 16 (pad to 1168), K=256 in 8 chunks of 32.
__global__ __launch_bounds__(256) void k_packWi(const float* __restrict__ Wi,
                                                u16* __restrict__ WiF){
  int f = blockIdx.x*256 + threadIdx.x;   // 37376 threads exactly
  int lane = f & 63, kk = (f>>6)&7, ji = f>>9;
  int g = lane>>4, c16 = lane&15;
  int j = ji*16 + c16;
  BF8 o;
  #pragma unroll
  for(int i=0;i<8;i++){
    int k = kk*32 + g*8 + i;
    o.h[i] = (j < 1160) ? f2bf(Wi[(size_t)k*1160 + j]) : (u16)0;
  }
  *(uint4*)(WiF + (size_t)f*8) = o.q;
}

// ---------------- K1b: pack Wo (512x256 f32) into MFMA B-fragment order, bf16 ----------------
__global__ __launch_bounds__(256) void k_pack(const float* __restrict__ Wo,
                                              u16* __restrict__ WF){
  int f = blockIdx.x*256 + threadIdx.x;   // 16384 threads
  int c16 = f&15, g=(f>>4)&3, kk=(f>>6)&15, ci=f>>10;
  int c = ci*16 + c16;
  #pragma unroll
  for(int i=0;i<8;i++){
    int k = kk*32 + g*8 + i;
    WF[(size_t)f*8 + i] = f2bf(Wo[(size_t)k*256 + c]);
  }
}

// ---------------- K1c: W1 (256x256 f32, row-major [o][c]) -> bf16 copy ----------------
__global__ __launch_bounds__(256) void k_packW1(const float* __restrict__ W1,
                                                u16* __restrict__ W1b){
  int i = (blockIdx.x*256 + threadIdx.x)*4;
  float4 v = *(const float4*)(W1 + i);
  W1b[i+0]=f2bf(v.x); W1b[i+1]=f2bf(v.y); W1b[i+2]=f2bf(v.z); W1b[i+3]=f2bf(v.w);
}

// ---------------- K1: in-projection GEMM (ONCE for both scan dirs) ----------------
// zxbcdt rows are direction-independent (H and V scans use the same rows, permuted).
// grid (10 col-blocks, 128 row-blocks), block 512 = 8 waves (2 row x 4 col).
// cb 0..3 -> z (silu -> zg); cb 4..8 -> xBC (bf16 -> xbc); cb 9 -> dt (softplus).
__global__ __launch_bounds__(512, 4) void k_gemm_in(const u16* __restrict__ xn,
    const u16* __restrict__ WiF, const float* __restrict__ dtb,
    const float* __restrict__ alog,
    u16* __restrict__ zg, u16* __restrict__ xbc,
    float* __restrict__ dtp, float* __restrict__ dtA){
  __shared__ u16 XL[128][264];     // A tile 128x256 bf16, pad 264
  int cb = blockIdx.x, rb = blockIdx.y;
  int t = threadIdx.x;
  int w = t>>6, lane = t&63, g = lane>>4, c16 = lane&15;
  int wr = w>>2, wc = w&3;

  // stage A: rows rb*128 .. +128, cols 0..255
  const u16* asrc = xn + (size_t)rb*128*256;
  #pragma unroll
  for(int i=0;i<8;i++){
    int idx = t + 512*i;
    int row = idx>>5, ch = idx&31;
    *(uint4*)&XL[row][ch*8] = *(const uint4*)(asrc + (size_t)row*256 + ch*8);
  }
  __syncthreads();

  #define AF(li,kk) (*(const short8*)&XL[wr*64 + (li)*16 + c16][(kk)*32 + g*8])

  int mbase = rb*128 + wr*64;
  #pragma unroll 1
  for(int jj=0;jj<2;++jj){
    int ji = cb*8 + wc*2 + jj;
    if(ji >= 73) continue;                 // cb==9 pad tiles
    f32x4 a0={0.f,0.f,0.f,0.f}, a1=a0, a2=a0, a3=a0;
    #pragma unroll
    for(int kk=0;kk<8;++kk){
      short8 bf = ldg_frag(WiF + ((size_t)(ji*8+kk)*64 + lane)*8);
      a0 = MFMA16(AF(0,kk), bf, a0);
      a1 = MFMA16(AF(1,kk), bf, a1);
      a2 = MFMA16(AF(2,kk), bf, a2);
      a3 = MFMA16(AF(3,kk), bf, a3);
    }
    if(ji < 32){                           // z -> silu -> zg
      int col = ji*16 + c16;
      #pragma unroll
      for(int r2=0;r2<4;r2++){
        zg[(size_t)(mbase +  0 + g*4 + r2)*512 + col] = f2bf(siluf(a0[r2]));
        zg[(size_t)(mbase + 16 + g*4 + r2)*512 + col] = f2bf(siluf(a1[r2]));
        zg[(size_t)(mbase + 32 + g*4 + r2)*512 + col] = f2bf(siluf(a2[r2]));
        zg[(size_t)(mbase + 48 + g*4 + r2)*512 + col] = f2bf(siluf(a3[r2]));
      }
    } else if(ji < 72){                    // xBC raw (pre-conv), bf16
      int col = ji*16 + c16 - 512;
      #pragma unroll
      for(int r2=0;r2<4;r2++){
        xbc[(size_t)(mbase +  0 + g*4 + r2)*640 + col] = f2bf(a0[r2]);
        xbc[(size_t)(mbase + 16 + g*4 + r2)*640 + col] = f2bf(a1[r2]);
        xbc[(size_t)(mbase + 32 + g*4 + r2)*640 + col] = f2bf(a2[r2]);
        xbc[(size_t)(mbase + 48 + g*4 + r2)*640 + col] = f2bf(a3[r2]);
      }
    } else if(c16 < 8){                    // dt (cols 1152..1159)
      int hd = c16;
      float A = -expf(alog[hd]);
      float bias = dtb[hd];
      #pragma unroll
      for(int li=0;li<4;li++){
        f32x4 a = (li==0)?a0 : (li==1)?a1 : (li==2)?a2 : a3;
        #pragma unroll
        for(int r2=0;r2<4;r2++){
          int m = mbase + li*16 + g*4 + r2;
          float v = a[r2] + bias;
          float sp = (v>20.f)? v : log1pf(expf(v));
          dtp[(size_t)((m>>6)*8 + hd)*64 + (m&63)] = sp;
          dtA[(size_t)((m>>6)*8 + hd)*64 + (m&63)] = sp*A;
        }
      }
    }
  }
  #undef AF
}

// ---------------- K1d: depthwise conv (fwd+bwd senses) along scan axis ----------------
// grid 256 (seq), block 640 (channel per thread), dirV selects axis.
// Outputs xf/xbw in (seq, pos, C) scan order.
__global__ __launch_bounds__(640) void k_conv(const u16* __restrict__ xbc,
    const float* __restrict__ convw, const float* __restrict__ convb,
    u16* __restrict__ xf, u16* __restrict__ xbw, int dirV){
  int s = blockIdx.x;
  int c = threadIdx.x;                     // 0..639
  int b = s>>6, r = s&63;
  float4 cw = *(const float4*)(convw + c*4);
  float cb_ = convb[c];
  size_t A0 = dirV ? ((size_t)(b*4096 + r)*640 + c) : ((size_t)s*64*640 + c);
  size_t S  = dirV ? (size_t)64*640 : (size_t)640;
  const u16* pin = xbc + A0;
  u16* pf = xf  + (size_t)s*64*640 + c;
  u16* pb = xbw + (size_t)s*64*640 + c;
  float fx1=0.f,fx2=0.f,fx3=0.f, by1=0.f,by2=0.f,by3=0.f;
  #pragma unroll 4
  for(int l=0;l<64;++l){
    float fx0 = bf2f(pin[(size_t)l*S]);
    float by0 = bf2f(pin[(size_t)(63-l)*S]);
    float of = cb_ + cw.w*fx0 + cw.z*fx1 + cw.y*fx2 + cw.x*fx3;
    float ob = cb_ + cw.w*by0 + cw.z*by1 + cw.y*by2 + cw.x*by3;
    pf[l*640] = f2bf(siluf(of));
    pb[l*640] = f2bf(siluf(ob));
    fx3=fx2; fx2=fx1; fx1=fx0;
    by3=by2; by2=by1; by1=by0;
  }
}

// ---------------- K2: SSD-form scan (MFMA) + gate + RMSNorm + out-proj (MFMA) ----------------
__global__ __launch_bounds__(512, 2) void k_scan(
    const u16* __restrict__ xf, const u16* __restrict__ xbw,
    const float* __restrict__ dtp_g, const float* __restrict__ dtA_g,
    const u16* __restrict__ zg, const float* __restrict__ dskip,
    const float* __restrict__ normw, const u16* __restrict__ WF,
    u16* __restrict__ fout, int dirV){
  // LDS: U [64][520] bf16 | XV [64][520] bf16 | G [64][68] f32 | sL,dtL,nwL
  __shared__ __align__(16) char smem[156672];
  u16 (*U)[520]   = (u16(*)[520])smem;
  u16 (*XV)[520]  = (u16(*)[520])(smem + 66560);
  float (*Gl)[68] = (float(*)[68])(smem + 133120);
  float* sL  = (float*)(smem + 150528);
  float* dtL = (float*)(smem + 152576);
  float* nwL = (float*)(smem + 154624);

  int s = blockIdx.x, t = threadIdx.x;
  int w = t>>6, lane = t&63, g = lane>>4, c16 = lane&15;
  nwL[t] = normw[t];
  float dsk = dskip[w];

  #pragma unroll 1
  for(int dirb=0; dirb<2; ++dirb){
    __syncthreads();   // dir1: prior V reads / U writes done before restage
    const u16* xb = (dirb? xbw : xf) + (size_t)s*64*640;
    // ---- per-head prefix sum of dt*A in scan coords (wave-local) ----
    {
      int tt = dirb ? 63-lane : lane;
      size_t dti = dirV ? ((size_t)(((s>>6)*64 + tt)*8 + w))*64 + (s&63)
                        : ((size_t)(s*8 + w))*64 + tt;
      float a = dtA_g[dti];
      float d = dtp_g[dti];
      #pragma unroll
      for(int off=1; off<64; off<<=1){
        float nb = __shfl_up(a, off, 64);
        if(lane >= off) a += nb;
      }
      sL[w*64+lane] = a;
      dtL[w*64+lane] = d;
    }
    // ---- G = C @ B^T : wave w computes 16x16 tiles 2w, 2w+1 ----
    #pragma unroll
    for(int tt2=0; tt2<2; ++tt2){
      int tile = 2*w + tt2, li = tile>>2, ji = tile&3;
      f32x4 acc = {0.f,0.f,0.f,0.f};
      #pragma unroll
      for(int kk=0; kk<2; ++kk){
        short8 af = ldg_frag(xb + (size_t)(li*16 + c16)*640 + 576 + kk*32 + g*8); // C rows
        short8 bf = ldg_frag(xb + (size_t)(ji*16 + c16)*640 + 512 + kk*32 + g*8); // B rows
        acc = MFMA16(af, bf, acc);
      }
      #pragma unroll
      for(int r=0;r<4;r++) Gl[li*16 + g*4 + r][ji*16 + c16] = acc[r];
    }
    // ---- stage X (cols 0..511) into XV ----
    #pragma unroll
    for(int it=0; it<8; ++it){
      int tr = (t>>6) + 8*it;
      int c0 = (t&63)*8;
      uint4 v = *(const uint4*)(xb + (size_t)tr*640 + c0);
      *(uint4*)&XV[tr][c0] = v;
    }
    __syncthreads();
    // ---- X-frags preload ----
    short8 xfr[4][2];
    #pragma unroll
    for(int pi=0; pi<4; ++pi){
      #pragma unroll
      for(int kk=0; kk<2; ++kk){
        BF8 u;
        #pragma unroll
        for(int i=0;i<8;i++){
          int uu = kk*32 + g*8 + i;
          u.h[i] = XV[uu][w*64 + pi*16 + c16];
        }
        xfr[pi][kk] = u.v;
      }
    }
    // ---- per l-tile: build M fragments, Y = M@X, gate, write V ----
    #pragma unroll 1
    for(int li=0; li<4; ++li){
      int tr = li*16 + c16;            // A-frag row (scan coord)
      float sl = sL[w*64 + tr];
      short8 mfr[2];
      #pragma unroll
      for(int kk=0; kk<2; ++kk){
        BF8 u;
        #pragma unroll
        for(int i=0;i<8;i++){
          int uu = kk*32 + g*8 + i;
          float m = 0.f;
          if(uu <= tr){
            m = __expf(sl - sL[w*64+uu]) * dtL[w*64+uu] * Gl[tr][uu];
            if(uu == tr) m += dsk;     // Dskip folded into diagonal (exact)
          }
          u.h[i] = f2bf(m);
        }
        mfr[kk] = u.v;
      }
      #pragma unroll
      for(int pi=0; pi<4; ++pi){
        f32x4 acc = {0.f,0.f,0.f,0.f};
        acc = MFMA16(mfr[0], xfr[pi][0], acc);
        acc = MFMA16(mfr[1], xfr[pi][1], acc);
        #pragma unroll
        for(int r=0;r<4;r++){
          int trow = li*16 + g*4 + r;
          int lorig = dirb ? 63-trow : trow;
          int c = w*64 + pi*16 + c16;
          size_t zrow = dirV ? ((size_t)(s>>6)*4096 + (size_t)lorig*64 + (s&63))
                             : ((size_t)s*64 + lorig);
          float zv = bf2f(zg[zrow*512 + c]);  // silu(z) pre-applied
          XV[lorig][c] = f2bf(acc[r] * zv);
        }
      }
    }
    __syncthreads();
    // ---- RMSNorm per row (over 512), accumulate 0.5*v*rs*normw into U ----
    #pragma unroll 1
    for(int rr=0; rr<8; ++rr){
      int l = w*8 + rr;
      BF8 u; u.q = *(const uint4*)&XV[l][lane*8];
      float vv[8]; float ss = 0.f;
      #pragma unroll
      for(int i=0;i<8;i++){ vv[i] = bf2f(u.h[i]); ss += vv[i]*vv[i]; }
      #pragma unroll
      for(int off=32; off>=1; off>>=1) ss += __shfl_xor(ss, off, 64);
      float rs = rsqrtf(ss*(1.f/512.f) + EPSF);
      BF8 o;
      if(dirb==0){
        #pragma unroll
        for(int i=0;i<8;i++) o.h[i] = f2bf(0.5f*vv[i]*rs*nwL[lane*8+i]);
      } else {
        BF8 p; p.q = *(const uint4*)&U[l][lane*8];
        #pragma unroll
        for(int i=0;i<8;i++) o.h[i] = f2bf(bf2f(p.h[i]) + 0.5f*vv[i]*rs*nwL[lane*8+i]);
      }
      *(uint4*)&U[l][lane*8] = o.q;
    }
  }
  __syncthreads();
  // ---- out-proj: fout[64][256] = U[64][512] @ Wo ----
  #pragma unroll 1
  for(int ci0=0; ci0<2; ++ci0){
    int ci = w*2 + ci0;
    f32x4 acc0={0.f,0.f,0.f,0.f}, acc1=acc0, acc2=acc0, acc3=acc0;
    #pragma unroll 2
    for(int kk=0; kk<16; ++kk){
      short8 bfr = ldg_frag(WF + (size_t)((((ci*16+kk)*4+g)*16+c16)*8));
      short8 a0 = *(const short8*)&U[ 0+c16][kk*32+g*8];
      short8 a1 = *(const short8*)&U[16+c16][kk*32+g*8];
      short8 a2 = *(const short8*)&U[32+c16][kk*32+g*8];
      short8 a3 = *(const short8*)&U[48+c16][kk*32+g*8];
      acc0 = MFMA16(a0,bfr,acc0); acc1 = MFMA16(a1,bfr,acc1);
      acc2 = MFMA16(a2,bfr,acc2); acc3 = MFMA16(a3,bfr,acc3);
    }
    #define WR_TILE(LI, ACC) { \
      _Pragma("unroll") \
      for(int r=0;r<4;r++) \
        fout[((size_t)(s*64 + LI*16 + g*4 + r))*256 + ci*16 + c16] = f2bf(ACC[r]); }
    WR_TILE(0, acc0) WR_TILE(1, acc1) WR_TILE(2, acc2) WR_TILE(3, acc3)
    #undef WR_TILE
  }
}

// ---------------- K3: blend f_H/f_V (bf16) + 1x1 conv on MFMA + partial stats ----------------
__global__ __launch_bounds__(512) void k_blendgemm(const u16* __restrict__ fH,
    const u16* __restrict__ fV, const float* __restrict__ Q1,
    const float* __restrict__ Sx, const u16* __restrict__ W1b,
    float* __restrict__ out, float* __restrict__ stats){
  __shared__ u16 fg[64][264];              // blended tile, bf16
  __shared__ float asL[64], bsL[64];
  __shared__ float red[16];
  int blk = blockIdx.x; int bb = blk>>6, h = blk&63;
  int t = threadIdx.x;
  if(t<64){
    float qv = Q1[bb*4096 + h*64 + t];
    float sv = Sx[bb*4096 + h*64 + t];
    float al = sigf(qv);
    float sc = 0.5f + 0.5f*sv;
    asL[t] = al*sc; bsL[t] = (1.f-al)*sc;
  }
  __syncthreads();
  {
    int w = t>>3, cb = (t&7)*8;
    float aw = asL[w], bw = bsL[w];
    const u16* ph = fH + ((size_t)((bb*64+h)*64 + w))*256;
    const u16* pv = fV + ((size_t)((bb*64+w)*64 + h))*256;
    #pragma unroll
    for(int j=0;j<4;j++){
      int c0 = cb + j*64;
      BF8 a, b, o;
      a.q = *(const uint4*)(ph + c0);
      b.q = *(const uint4*)(pv + c0);
      #pragma unroll
      for(int i=0;i<8;i++) o.h[i] = f2bf(aw*bf2f(a.h[i]) + bw*bf2f(b.h[i]));
      *(uint4*)&fg[w][c0] = o.q;
    }
  }
  __syncthreads();
  int wv = t>>6, lane = t&63, g = lane>>4, c16 = lane&15;
  f32x4 acc[4][2];
  #pragma unroll
  for(int pi=0;pi<4;pi++){ acc[pi][0]=(f32x4){0.f,0.f,0.f,0.f}; acc[pi][1]=acc[pi][0]; }
  #pragma unroll 2
  for(int kk=0; kk<8; ++kk){
    short8 b0 = ldg_frag(W1b + (size_t)((wv*2+0)*16 + c16)*256 + kk*32 + g*8);
    short8 b1 = ldg_frag(W1b + (size_t)((wv*2+1)*16 + c16)*256 + kk*32 + g*8);
    #pragma unroll
    for(int pi=0; pi<4; ++pi){
      short8 a = *(const short8*)&fg[pi*16 + c16][kk*32 + g*8];
      acc[pi][0] = MFMA16(a, b0, acc[pi][0]);
      acc[pi][1] = MFMA16(a, b1, acc[pi][1]);
    }
  }
  float s1=0.f, s2=0.f;
  #pragma unroll
  for(int pi=0;pi<4;pi++){
    #pragma unroll
    for(int j=0;j<2;j++){
      int o = (wv*2+j)*16 + c16;
      int w0 = pi*16 + g*4;
      float4 vv = {acc[pi][j][0], acc[pi][j][1], acc[pi][j][2], acc[pi][j][3]};
      s1 += (vv.x+vv.y)+(vv.z+vv.w);
      s2 += (vv.x*vv.x+vv.y*vv.y)+(vv.z*vv.z+vv.w*vv.w);
      *(float4*)(out + (((size_t)(bb*256+o)*64 + h)*64 + w0)) = vv;
    }
  }
  #pragma unroll
  for(int off=32;off>=1;off>>=1){ s1+=__shfl_xor(s1,off,64); s2+=__shfl_xor(s2,off,64); }
  if(lane==0){ red[wv]=s1; red[8+wv]=s2; }
  __syncthreads();
  if(t==0){
    float a=0.f,b=0.f;
    #pragma unroll
    for(int i=0;i<8;i++){ a+=red[i]; b+=red[8+i]; }
    stats[blk*2+0]=a; stats[blk*2+1]=b;
  }
}

// ---------------- K4: per-batch global norm + exact GELU, in place on d_out ----------------
__global__ __launch_bounds__(256) void k_final(float* __restrict__ out,
    const float* __restrict__ stats, const float* __restrict__ gg,
    const float* __restrict__ gb){
  __shared__ float red[64][2];
  __shared__ float mv[2];
  int blk = blockIdx.x; int bb = blk>>6, h = blk&63;
  int t = threadIdx.x;
  if(t<64){ red[t][0] = stats[(bb*64+t)*2+0]; red[t][1] = stats[(bb*64+t)*2+1]; }
  __syncthreads();
  if(t==0){
    float s1=0.f,s2=0.f;
    for(int i=0;i<64;i++){ s1+=red[i][0]; s2+=red[i][1]; }
    float mu = s1*(1.f/1048576.f);
    float var = s2*(1.f/1048576.f) - mu*mu;
    mv[0]=mu; mv[1]=rsqrtf(var+EPSF);
  }
  __syncthreads();
  float mu = mv[0], rs = mv[1];
  for(int i=0;i<64;i++){ int idx=t+256*i; int o=idx>>6, w=idx&63;
    size_t gidx = (size_t)((bb*256+o)*64+h)*64+w;
    float v = out[gidx];
    float yn = (v-mu)*rs*gg[o] + gb[o];
    out[gidx] = 0.5f*yn*(1.f+erff(yn*0.70710678118654752f));
  }
}

extern "C" void kernel_launch(void* const* d_in, const int* in_sizes, int n_in,
                              void* d_out, int out_size, void* d_ws, size_t ws_size,
                              hipStream_t stream) {
  const float* x     = (const float*)d_in[0];
  const float* Q1    = (const float*)d_in[1];
  // d_in[2] = Q2 : unused by the reference
  const float* Sx    = (const float*)d_in[3];
  const float* lng   = (const float*)d_in[4];
  const float* lnb   = (const float*)d_in[5];
  const float* Wi    = (const float*)d_in[6];
  const float* convw = (const float*)d_in[7];
  const float* convb = (const float*)d_in[8];
  const float* dtb   = (const float*)d_in[9];
  const float* alog  = (const float*)d_in[10];
  const float* dskip = (const float*)d_in[11];
  const float* normw = (const float*)d_in[12];
  const float* Wo    = (const float*)d_in[13];
  const float* gg    = (const float*)d_in[14];
  const float* gb    = (const float*)d_in[15];
  const float* W1    = (const float*)d_in[16];
  float* out = (float*)d_out;
  char* ws = (char*)d_ws;

  // ws layout (~102 MiB):
  size_t o = 0;
  u16*   xnb  = (u16*)(ws + o);  o += (size_t)16384*256*2;        // 8 MB  xn bf16
  u16*   fHb  = (u16*)(ws + o);  o += (size_t)16384*256*2;        // 8 MB
  u16*   fVb  = (u16*)(ws + o);  o += (size_t)16384*256*2;        // 8 MB
  u16*   zgb  = (u16*)(ws + o);  o += (size_t)16384*512*2;        // 16 MB
  u16*   xbc  = (u16*)(ws + o);  o += (size_t)16384*640*2;        // 20 MB raw xBC
  u16*   xfb  = (u16*)(ws + o);  o += (size_t)16384*640*2;        // 20 MB (shared H/V)
  u16*   xbb  = (u16*)(ws + o);  o += (size_t)16384*640*2;        // 20 MB (shared H/V)
  float* dtp  = (float*)(ws + o); o += (size_t)131072*4;          // 0.5 MB
  float* dtA  = (float*)(ws + o); o += (size_t)131072*4;          // 0.5 MB
  float* stats= (float*)(ws + o); o += 4096;
  u16*   WF   = (u16*)(ws + o);  o += (size_t)16384*8*2;          // 256 KB
  u16*   W1b  = (u16*)(ws + o);  o += (size_t)65536*2;            // 128 KB
  u16*   WiF  = (u16*)(ws + o);  o += (size_t)73*8*64*8*2;        // 584 KB

  k_ln<<<256, 256, 0, stream>>>(x, lng, lnb, xnb);
  k_packWi<<<146, 256, 0, stream>>>(Wi, WiF);
  k_pack<<<64, 256, 0, stream>>>(Wo, WF);
  k_packW1<<<64, 256, 0, stream>>>(W1, W1b);
  k_gemm_in<<<dim3(10,128), 512, 0, stream>>>(xnb, WiF, dtb, alog,
                                              zgb, xbc, dtp, dtA);
  for(int dir=0; dir<2; dir++){
    k_conv<<<256, 640, 0, stream>>>(xbc, convw, convb, xfb, xbb, dir);
    k_scan<<<256, 512, 0, stream>>>(xfb, xbb, dtp, dtA, zgb, dskip, normw, WF,
                                    dir ? fVb : fHb, dir);
  }
  k_blendgemm<<<256, 512, 0, stream>>>(fHb, fVb, Q1, Sx, W1b, out, stats);
  k_final<<<256, 256, 0, stream>>>(out, stats, gg, gb);
}